// Round 5
// baseline (180.259 us; speedup 1.0000x reference)
//
#include <hip/hip_runtime.h>

// Problem constants
constexpr int   FRAMES   = 128 * 1024;   // B*T = 131072
constexpr int   NB       = 50;           // bones (== joints)
constexpr int   FRAME_F  = 150;          // floats per frame
// final = 0.1 * (sum_abs + 0.1*sum_sq) / (FRAMES*150)
constexpr float SCALE    = 0.1f / (float)(FRAMES * FRAME_F);

constexpr int FPB   = 16;                // frames per block
constexpr int FLTS  = FPB * FRAME_F;     // 2400 floats per array per block
constexpr int VECS  = FLTS / 4;          // 600 float4
constexpr int NBLK  = FRAMES / FPB;      // 8192 blocks
constexpr int TASKS = FPB * NB;          // 800 bone tasks per block

// 19.2 KB LDS -> 8 blocks/CU -> 100% occupancy (32 waves/CU)
__global__ __launch_bounds__(256, 8) void bone_loss_main(
    const float* __restrict__ preds,
    const float* __restrict__ targets,
    float* __restrict__ partials)
{
    __shared__ float4 sp4[VECS];
    __shared__ float4 st4[VECS];
    float* sp = (float*)sp4;
    float* st = (float*)st4;

    // ---- stage 16 frames of both arrays, fully coalesced float4 ----
    // (LDS stores pin these loads: the compiler cannot sink them into compute)
    const long base = (long)blockIdx.x * FLTS;
    const float4* gp = (const float4*)(preds + base);
    const float4* gt = (const float4*)(targets + base);
    #pragma unroll
    for (int i = threadIdx.x; i < VECS; i += 256) {
        sp4[i] = gp[i];
        st4[i] = gt[i];
    }
    __syncthreads();

    // ---- compute: one bone task per loop iteration ----
    float acc = 0.0f;
    #pragma unroll
    for (int t = threadIdx.x; t < TASKS; t += 256) {
        const int f  = t / NB;
        const int b  = t - f * NB;
        const int jb = (b == NB - 1) ? 0 : b + 1;
        const int bi = f * FRAME_F + b * 3;
        const int bj = f * FRAME_F + jb * 3;

        const float p0 = sp[bi], p1 = sp[bi+1], p2 = sp[bi+2];
        const float q0 = sp[bj], q1 = sp[bj+1], q2 = sp[bj+2];
        const float t0 = st[bi], t1 = st[bi+1], t2 = st[bi+2];
        const float u0 = st[bj], u1 = st[bj+1], u2 = st[bj+2];

        // mask: targets*mask == targets identically; only preds needs masking
        const float m0 = (t0 != 0.0f) ? 1.0f : 0.0f;
        const float m1 = (t1 != 0.0f) ? 1.0f : 0.0f;
        const float m2 = (t2 != 0.0f) ? 1.0f : 0.0f;
        const float n0 = (u0 != 0.0f) ? 1.0f : 0.0f;
        const float n1 = (u1 != 0.0f) ? 1.0f : 0.0f;
        const float n2 = (u2 != 0.0f) ? 1.0f : 0.0f;

        const float pm0 = p0 * m0, pm1 = p1 * m1, pm2 = p2 * m2;
        const float qm0 = q0 * n0, qm1 = q1 * n1, qm2 = q2 * n2;

        // L1 term over this task's owned joint (joint b)
        const float ab = fabsf(pm0 - t0) + fabsf(pm1 - t1) + fabsf(pm2 - t2);

        // bone diffs
        const float pd0 = pm0 - qm0, pd1 = pm1 - qm1, pd2 = pm2 - qm2;
        const float td0 = t0  - u0,  td1 = t1  - u1,  td2 = t2  - u2;

        const float pl2 = pd0*pd0 + pd1*pd1 + pd2*pd2;
        const float tl2 = td0*td0 + td1*td1 + td2*td2;
        // 1/(len+tiny): rsq approx (rel err ~1e-7, irrelevant to a mean), zero-guarded
        const float pri = (pl2 > 0.0f) ? __builtin_amdgcn_rsqf(pl2) : 0.0f;
        const float tri = (tl2 > 0.0f) ? __builtin_amdgcn_rsqf(tl2) : 0.0f;

        const float d0 = pd0 * pri - td0 * tri;
        const float d1 = pd1 * pri - td1 * tri;
        const float d2 = pd2 * pri - td2 * tri;
        const float sq = m0*d0*d0 + m1*d1*d1 + m2*d2*d2;   // re-mask ([:150] slice)

        acc += ab + 0.1f * sq;
    }

    // ---- block reduction ----
    #pragma unroll
    for (int off = 32; off > 0; off >>= 1)
        acc += __shfl_down(acc, off, 64);

    __shared__ float ws[4];
    const int wid = threadIdx.x >> 6;
    if ((threadIdx.x & 63) == 0) ws[wid] = acc;
    __syncthreads();
    if (threadIdx.x == 0)
        partials[blockIdx.x] = ws[0] + ws[1] + ws[2] + ws[3];
}

__global__ __launch_bounds__(256) void bone_loss_finish(
    const float* __restrict__ partials,
    float* __restrict__ out)
{
    float v = 0.0f;
    for (int i = threadIdx.x; i < NBLK; i += 256)
        v += partials[i];

    #pragma unroll
    for (int off = 32; off > 0; off >>= 1)
        v += __shfl_down(v, off, 64);

    __shared__ float ws[4];
    const int wid = threadIdx.x >> 6;
    if ((threadIdx.x & 63) == 0) ws[wid] = v;
    __syncthreads();
    if (threadIdx.x == 0)
        out[0] = (ws[0] + ws[1] + ws[2] + ws[3]) * SCALE;
}

extern "C" void kernel_launch(void* const* d_in, const int* in_sizes, int n_in,
                              void* d_out, int out_size, void* d_ws, size_t ws_size,
                              hipStream_t stream) {
    const float* preds   = (const float*)d_in[0];
    const float* targets = (const float*)d_in[1];
    float* out      = (float*)d_out;
    float* partials = (float*)d_ws;       // NBLK floats = 32 KB

    bone_loss_main<<<NBLK, 256, 0, stream>>>(preds, targets, partials);
    bone_loss_finish<<<1, 256, 0, stream>>>(partials, out);
}

// Round 6
// 177.253 us; speedup vs baseline: 1.0170x; 1.0170x over previous
//
#include <hip/hip_runtime.h>

// Problem constants
constexpr int   FRAMES   = 128 * 1024;   // B*T = 131072
constexpr int   NB       = 50;           // bones (== joints)
constexpr int   FRAME_F  = 150;          // floats per frame
// final = 0.1 * (sum_abs + 0.1*sum_sq) / (FRAMES*150)
constexpr float SCALE    = 0.1f / (float)(FRAMES * FRAME_F);

constexpr int FPB   = 16;                // frames per block
constexpr int FLTS  = FPB * FRAME_F;     // 2400 floats per array per block
constexpr int VECS  = FLTS / 4;          // 600 float4
constexpr int NBLK  = FRAMES / FPB;      // 8192 blocks
constexpr int TASKS = FPB * NB;          // 800 bone tasks per block

#define GLOBAL_AS(x) ((__attribute__((address_space(1))) const void*)(x))
#define LDS_AS(x)    ((__attribute__((address_space(3))) void*)(x))

// 19.2 KB LDS -> 8 blocks/CU -> full occupancy target
__global__ __launch_bounds__(256, 8) void bone_loss_main(
    const float* __restrict__ preds,
    const float* __restrict__ targets,
    float* __restrict__ partials)
{
    __shared__ float4 sp4[VECS];
    __shared__ float4 st4[VECS];
    float* sp = (float*)sp4;
    float* st = (float*)st4;

    // ---- stage 16 frames via async global->LDS DMA (no VGPR round trip).
    // Fire-and-forget: all ~19 wave-instructions issue back-to-back, so
    // ~19 KB/wave is in flight vs ~2 KB with load+ds_write staging.
    // Destination is wave-uniform base + lane*16 (thread t -> sp4[t], stride
    // 256), exactly the HW constraint; tail iteration masks a lane-suffix.
    const long base = (long)blockIdx.x * FLTS;
    const float4* gp = (const float4*)(preds + base);
    const float4* gt = (const float4*)(targets + base);
    #pragma unroll
    for (int i = threadIdx.x; i < VECS; i += 256) {
        __builtin_amdgcn_global_load_lds(GLOBAL_AS(gp + i), LDS_AS(&sp4[i]), 16, 0, 0);
        __builtin_amdgcn_global_load_lds(GLOBAL_AS(gt + i), LDS_AS(&st4[i]), 16, 0, 0);
    }
    __syncthreads();   // compiler emits s_waitcnt vmcnt(0) before s_barrier

    // ---- compute: one bone task per loop iteration ----
    float acc = 0.0f;
    #pragma unroll
    for (int t = threadIdx.x; t < TASKS; t += 256) {
        const int f  = t / NB;
        const int b  = t - f * NB;
        const int jb = (b == NB - 1) ? 0 : b + 1;
        const int bi = f * FRAME_F + b * 3;
        const int bj = f * FRAME_F + jb * 3;

        const float p0 = sp[bi], p1 = sp[bi+1], p2 = sp[bi+2];
        const float q0 = sp[bj], q1 = sp[bj+1], q2 = sp[bj+2];
        const float t0 = st[bi], t1 = st[bi+1], t2 = st[bi+2];
        const float u0 = st[bj], u1 = st[bj+1], u2 = st[bj+2];

        // mask: targets*mask == targets identically; only preds needs masking
        const float m0 = (t0 != 0.0f) ? 1.0f : 0.0f;
        const float m1 = (t1 != 0.0f) ? 1.0f : 0.0f;
        const float m2 = (t2 != 0.0f) ? 1.0f : 0.0f;
        const float n0 = (u0 != 0.0f) ? 1.0f : 0.0f;
        const float n1 = (u1 != 0.0f) ? 1.0f : 0.0f;
        const float n2 = (u2 != 0.0f) ? 1.0f : 0.0f;

        const float pm0 = p0 * m0, pm1 = p1 * m1, pm2 = p2 * m2;
        const float qm0 = q0 * n0, qm1 = q1 * n1, qm2 = q2 * n2;

        // L1 term over this task's owned joint (joint b)
        const float ab = fabsf(pm0 - t0) + fabsf(pm1 - t1) + fabsf(pm2 - t2);

        // bone diffs
        const float pd0 = pm0 - qm0, pd1 = pm1 - qm1, pd2 = pm2 - qm2;
        const float td0 = t0  - u0,  td1 = t1  - u1,  td2 = t2  - u2;

        const float pl2 = pd0*pd0 + pd1*pd1 + pd2*pd2;
        const float tl2 = td0*td0 + td1*td1 + td2*td2;
        // 1/(len+tiny): rsq approx (rel err ~1e-7, irrelevant to a mean), zero-guarded
        const float pri = (pl2 > 0.0f) ? __builtin_amdgcn_rsqf(pl2) : 0.0f;
        const float tri = (tl2 > 0.0f) ? __builtin_amdgcn_rsqf(tl2) : 0.0f;

        const float d0 = pd0 * pri - td0 * tri;
        const float d1 = pd1 * pri - td1 * tri;
        const float d2 = pd2 * pri - td2 * tri;
        const float sq = m0*d0*d0 + m1*d1*d1 + m2*d2*d2;   // re-mask ([:150] slice)

        acc += ab + 0.1f * sq;
    }

    // ---- block reduction ----
    #pragma unroll
    for (int off = 32; off > 0; off >>= 1)
        acc += __shfl_down(acc, off, 64);

    __shared__ float ws[4];
    const int wid = threadIdx.x >> 6;
    if ((threadIdx.x & 63) == 0) ws[wid] = acc;
    __syncthreads();
    if (threadIdx.x == 0)
        partials[blockIdx.x] = ws[0] + ws[1] + ws[2] + ws[3];
}

__global__ __launch_bounds__(256) void bone_loss_finish(
    const float* __restrict__ partials,
    float* __restrict__ out)
{
    float v = 0.0f;
    for (int i = threadIdx.x; i < NBLK; i += 256)
        v += partials[i];

    #pragma unroll
    for (int off = 32; off > 0; off >>= 1)
        v += __shfl_down(v, off, 64);

    __shared__ float ws[4];
    const int wid = threadIdx.x >> 6;
    if ((threadIdx.x & 63) == 0) ws[wid] = v;
    __syncthreads();
    if (threadIdx.x == 0)
        out[0] = (ws[0] + ws[1] + ws[2] + ws[3]) * SCALE;
}

extern "C" void kernel_launch(void* const* d_in, const int* in_sizes, int n_in,
                              void* d_out, int out_size, void* d_ws, size_t ws_size,
                              hipStream_t stream) {
    const float* preds   = (const float*)d_in[0];
    const float* targets = (const float*)d_in[1];
    float* out      = (float*)d_out;
    float* partials = (float*)d_ws;       // NBLK floats = 32 KB

    bone_loss_main<<<NBLK, 256, 0, stream>>>(preds, targets, partials);
    bone_loss_finish<<<1, 256, 0, stream>>>(partials, out);
}

// Round 7
// 175.981 us; speedup vs baseline: 1.0243x; 1.0072x over previous
//
#include <hip/hip_runtime.h>

// Problem constants
constexpr int   FRAMES   = 128 * 1024;   // B*T = 131072
constexpr int   NB       = 50;           // bones (== joints)
constexpr int   FRAME_F  = 150;          // floats per frame
// final = 0.1 * (sum_abs + 0.1*sum_sq) / (FRAMES*150)
constexpr float SCALE    = 0.1f / (float)(FRAMES * FRAME_F);

constexpr int FPW    = 16;                    // frames per wave
constexpr int NWAVES = FRAMES / FPW;          // 8192 waves
constexpr int BLOCK  = 256;                   // 4 waves/block
constexpr int NBLK   = NWAVES * 64 / BLOCK;   // 2048 blocks

__global__ __launch_bounds__(256) void bone_loss_main(
    const float* __restrict__ preds,
    const float* __restrict__ targets,
    float* __restrict__ partials)
{
    const int gid   = blockIdx.x * BLOCK + threadIdx.x;
    const int wave  = gid >> 6;
    const int lane  = threadIdx.x & 63;
    const bool act  = lane < NB;
    const int  jcl  = act ? lane : (NB - 1);          // clamp inactive lanes
    const int  sidx = (lane >= NB - 1) ? lane - (NB - 1) : lane + 1;  // (lane+1)%50

    const long fbase = (long)wave * FPW;
    const float* pp = preds   + fbase * FRAME_F + jcl * 3;
    const float* tp = targets + fbase * FRAME_F + jcl * 3;

    // ---- phase 1: issue ALL 32 dwordx3 loads (19.2 KB/wave in flight) ----
    float P[FPW][3], T[FPW][3];
    #pragma unroll
    for (int i = 0; i < FPW; ++i) {
        const float* a = pp + i * FRAME_F;
        const float* b = tp + i * FRAME_F;
        P[i][0] = a[0]; P[i][1] = a[1]; P[i][2] = a[2];
        T[i][0] = b[0]; T[i][1] = b[1]; T[i][2] = b[2];
    }
    // Memory clobber: sinking any of the above loads past this point is
    // illegal for the compiler, so all 32 stay issued back-to-back. The
    // compiler still emits fine-grained vmcnt(N) waits in the consume loop,
    // so frame-0 compute overlaps frames 1..15 still in flight. No barrier.
    asm volatile("" ::: "memory");

    // ---- phase 2: compute, frame by frame (release order = issue order) ----
    float acc = 0.0f;
    #pragma unroll
    for (int i = 0; i < FPW; ++i) {
        const float p0 = P[i][0], p1 = P[i][1], p2 = P[i][2];
        const float t0 = T[i][0], t1 = T[i][1], t2 = T[i][2];

        // masks: targets*mask == targets identically; mask preds only
        const float m0 = (t0 != 0.0f) ? 1.0f : 0.0f;
        const float m1 = (t1 != 0.0f) ? 1.0f : 0.0f;
        const float m2 = (t2 != 0.0f) ? 1.0f : 0.0f;
        const float pm0 = p0 * m0, pm1 = p1 * m1, pm2 = p2 * m2;

        // L1 term over this lane's owned joint
        const float ab = fabsf(pm0 - t0) + fabsf(pm1 - t1) + fabsf(pm2 - t2);

        // neighbor joint via cross-lane: neighbor's masked-pred IS qm, raw t IS u
        const float qm0 = __shfl(pm0, sidx, 64);
        const float qm1 = __shfl(pm1, sidx, 64);
        const float qm2 = __shfl(pm2, sidx, 64);
        const float u0  = __shfl(t0,  sidx, 64);
        const float u1  = __shfl(t1,  sidx, 64);
        const float u2  = __shfl(t2,  sidx, 64);

        const float pd0 = pm0 - qm0, pd1 = pm1 - qm1, pd2 = pm2 - qm2;
        const float td0 = t0  - u0,  td1 = t1  - u1,  td2 = t2  - u2;

        const float pl2 = pd0*pd0 + pd1*pd1 + pd2*pd2;
        const float tl2 = td0*td0 + td1*td1 + td2*td2;
        // 1/(len+tiny): rsq approx (rel err ~1e-7, irrelevant to a mean), zero-guarded
        const float pri = (pl2 > 0.0f) ? __builtin_amdgcn_rsqf(pl2) : 0.0f;
        const float tri = (tl2 > 0.0f) ? __builtin_amdgcn_rsqf(tl2) : 0.0f;

        const float d0 = pd0 * pri - td0 * tri;
        const float d1 = pd1 * pri - td1 * tri;
        const float d2 = pd2 * pri - td2 * tri;
        const float sq = m0*d0*d0 + m1*d1*d1 + m2*d2*d2;   // re-mask ([:150] slice)

        acc += act ? (ab + 0.1f * sq) : 0.0f;
    }

    // ---- block reduction ----
    #pragma unroll
    for (int off = 32; off > 0; off >>= 1)
        acc += __shfl_down(acc, off, 64);

    __shared__ float ws[4];
    const int wid = threadIdx.x >> 6;
    if ((threadIdx.x & 63) == 0) ws[wid] = acc;
    __syncthreads();
    if (threadIdx.x == 0)
        partials[blockIdx.x] = ws[0] + ws[1] + ws[2] + ws[3];
}

__global__ __launch_bounds__(256) void bone_loss_finish(
    const float* __restrict__ partials,
    float* __restrict__ out)
{
    float v = 0.0f;
    for (int i = threadIdx.x; i < NBLK; i += 256)
        v += partials[i];

    #pragma unroll
    for (int off = 32; off > 0; off >>= 1)
        v += __shfl_down(v, off, 64);

    __shared__ float ws[4];
    const int wid = threadIdx.x >> 6;
    if ((threadIdx.x & 63) == 0) ws[wid] = v;
    __syncthreads();
    if (threadIdx.x == 0)
        out[0] = (ws[0] + ws[1] + ws[2] + ws[3]) * SCALE;
}

extern "C" void kernel_launch(void* const* d_in, const int* in_sizes, int n_in,
                              void* d_out, int out_size, void* d_ws, size_t ws_size,
                              hipStream_t stream) {
    const float* preds   = (const float*)d_in[0];
    const float* targets = (const float*)d_in[1];
    float* out      = (float*)d_out;
    float* partials = (float*)d_ws;       // NBLK floats = 8 KB

    bone_loss_main<<<NBLK, BLOCK, 0, stream>>>(preds, targets, partials);
    bone_loss_finish<<<1, 256, 0, stream>>>(partials, out);
}